// Round 11
// baseline (116.127 us; speedup 1.0000x reference)
//
#include <hip/hip_runtime.h>

#define NRES 384
#define NLIG 128
#define INC 384
#define OUTC 128
#define NTOT 512
#define GRID 256

// ---- f32 ws regions (float offsets) ----
#define WS_RI   0           // [384][32]
#define WS_RJ   12288       // [384][32]
#define WS_LI   24576       // [512][32]  (m*128+nl)
#define WS_LJ   40960       // [512][32]
#define WS_BF16 57344       // bf16 area starts here (float offset)
#define WS_CNT  3760128     // 2 x unsigned barrier counters (float offset)

// ---- bf16 regions (bf16-element offsets from WS_BF16) ----
#define BT_RR   0            // [384][o*32+y]
#define BT_RL   1572864
#define BT_LR   3145728
#define BT_LL   4718592      // [512][o*32+y]
#define BF_RJ   6815744      // [384][32]
#define BF_LJM  6828032      // [128][32]  mean_m l_j
#define BF_LIM  6832128      // [128][32]  mean_m l_i
#define BF_LJ   6836224      // [4*128][32]
#define BF_RI   6852608      // [384][32]
#define BF_LI   6864896      // [512][32]
#define BW_W    6881280      // 4 x [n=o*32+y][x] bf16

#define KW_STR 257

typedef __bf16 bf16x8 __attribute__((ext_vector_type(8)));
typedef __bf16 bf16x4 __attribute__((ext_vector_type(4)));
typedef float  f32x4  __attribute__((ext_vector_type(4)));

__device__ inline bf16x8 cvt8(const float* p) {
  f32x4 a = *(const f32x4*)p, b = *(const f32x4*)(p + 4);
  bf16x8 r;
  r[0] = (__bf16)a[0]; r[1] = (__bf16)a[1]; r[2] = (__bf16)a[2]; r[3] = (__bf16)a[3];
  r[4] = (__bf16)b[0]; r[5] = (__bf16)b[1]; r[6] = (__bf16)b[2]; r[7] = (__bf16)b[3];
  return r;
}

__device__ __forceinline__ void grid_barrier(unsigned* cnt, unsigned target) {
  __syncthreads();
  if (threadIdx.x == 0) {
    __hip_atomic_fetch_add(cnt, 1u, __ATOMIC_ACQ_REL, __HIP_MEMORY_SCOPE_AGENT);
    unsigned v;
    do {
      __builtin_amdgcn_s_sleep(2);
      v = __hip_atomic_load(cnt, __ATOMIC_RELAXED, __HIP_MEMORY_SCOPE_AGENT);
    } while (v < target);
  }
  __syncthreads();
  __threadfence();   // acquire: invalidate stale lines before cross-XCD reads
}

__global__ __launch_bounds__(256, 2) void fused_all(
    const float* __restrict__ rec, const float* __restrict__ lig,
    const float* __restrict__ rl1w, const float* __restrict__ rl1b,
    const float* __restrict__ rl2w, const float* __restrict__ rl2b,
    const float* __restrict__ ll1w, const float* __restrict__ ll1b,
    const float* __restrict__ ll2w, const float* __restrict__ ll2b,
    const float* __restrict__ Wrr, const float* __restrict__ Wrl,
    const float* __restrict__ Wlr, const float* __restrict__ Wll,
    const float* __restrict__ rrb, const float* __restrict__ rlb,
    const float* __restrict__ lrb, const float* __restrict__ llb,
    float* __restrict__ ws, float* __restrict__ out) {
  __shared__ float lds[32 * KW_STR];     // 32.9 KB
  unsigned* cnt = (unsigned*)(ws + WS_CNT);
  int b = blockIdx.x, t = threadIdx.x;
  __bf16* B16 = (__bf16*)(ws + WS_BF16);
  int l = t & 63, w = t >> 6;
  int lr16 = l & 15, lq = l >> 4;

  // ===================== phase 1: projections + W relayout ==================
  if (b < 28) {                    // projections via MFMA
    int pair = w >> 1, rh = w & 1;
    const float* in;
    const float *w1, *b1, *w2, *b2;
    float *o1, *o2;
    __bf16 *bf1, *bf2;
    int row0;
    if (b < 12) {
      row0 = b * 32;
      in = rec; w1 = rl1w; b1 = rl1b; w2 = rl2w; b2 = rl2b;
      o1 = ws + WS_RI; o2 = ws + WS_RJ;
      bf1 = B16 + BF_RI; bf2 = B16 + BF_RJ;
    } else {
      row0 = (b - 12) * 32;
      in = lig; w1 = ll1w; b1 = ll1b; w2 = ll2w; b2 = ll2b;
      o1 = ws + WS_LI; o2 = ws + WS_LJ;
      bf1 = B16 + BF_LI; bf2 = B16 + BF_LJ;
    }
    const float* wsrc = pair ? w2 : w1;
    const float* bsrc = pair ? b2 : b1;
    float* osrc = pair ? o2 : o1;
    __bf16* bdst = pair ? bf2 : bf1;
    int arow = row0 + rh * 16 + lr16;

    f32x4 acc[2];
#pragma unroll
    for (int ci = 0; ci < 2; ++ci) acc[ci] = (f32x4){0.f, 0.f, 0.f, 0.f};
    for (int ks = 0; ks < 12; ++ks) {
      bf16x8 af = cvt8(in + (size_t)arow * INC + ks * 32 + lq * 8);
#pragma unroll
      for (int ci = 0; ci < 2; ++ci) {
        int ch = ci * 16 + lr16;
        bf16x8 bf = cvt8(wsrc + (size_t)ch * INC + ks * 32 + lq * 8);
        acc[ci] = __builtin_amdgcn_mfma_f32_16x16x32_bf16(af, bf, acc[ci], 0, 0, 0);
      }
    }
#pragma unroll
    for (int ci = 0; ci < 2; ++ci) {
      int c = ci * 16 + lr16;
      float bias = bsrc[c];
#pragma unroll
      for (int e = 0; e < 4; ++e) {
        int r = row0 + rh * 16 + 4 * lq + e;
        float v = acc[ci][e] + bias;
        osrc[r * 32 + c] = v;
        bdst[r * 32 + c] = (__bf16)v;
      }
    }
  } else if (b < 92) {             // W relayout: Wb[n=o*32+y][x] bf16
    int bb = b - 28;               // 0..63
    int tt = bb >> 4, oc = bb & 15;
    const float* W = tt == 0 ? Wrr : tt == 1 ? Wrl : tt == 2 ? Wlr : Wll;
    __bf16* Wb = B16 + BW_W + tt * 131072;
    int o0 = oc * 8;
#pragma unroll
    for (int it = 0; it < 32; ++it) {
      int idx = it * 256 + t;      // 0..8191
      int oo = idx >> 10, r = idx & 1023;
      int x = r >> 5, y = r & 31;
      lds[x * KW_STR + oo * 32 + y] = W[(size_t)(o0 + oo) * 1024 + r];
    }
    __syncthreads();
#pragma unroll
    for (int it = 0; it < 32; ++it) {
      int idx = it * 256 + t;      // 0..8191
      int x = idx & 31, nl = idx >> 5;   // nl = oo*32+y
      Wb[(size_t)(o0 * 32 + nl) * 32 + x] = (__bf16)lds[x * KW_STR + nl];
    }
  }
  grid_barrier(cnt + 0, GRID);

  // ===================== phase 2: At = facB @ Wb^T + means ==================
  for (int u = b; u < 257; u += GRID) {
    if (u < 256) {
      int tt = u >> 6, sub = u & 63;
      int nt = sub >> 2, mq = sub & 3;
      const __bf16* facB;
      __bf16* At;
      int M;
      if (tt == 0)      { facB = B16 + BF_RI; At = B16 + BT_RR; M = 384; }
      else if (tt == 1) { facB = B16 + BF_RI; At = B16 + BT_RL; M = 384; }
      else if (tt == 2) { facB = B16 + BF_RJ; At = B16 + BT_LR; M = 384; }
      else              { facB = B16 + BF_LI; At = B16 + BT_LL; M = 512; }
      const __bf16* Wb = B16 + BW_W + tt * 131072;
      int n0w = nt * 256 + w * 64;
      int mtiles = M >> 6;         // per quarter: M/4/16
      int m0 = mq * (M >> 2);

      bf16x8 wv[4];
#pragma unroll
      for (int q = 0; q < 4; ++q)
        wv[q] = *(const bf16x8*)(Wb + (size_t)(n0w + q * 16 + lr16) * 32 + lq * 8);

      for (int mt = 0; mt < mtiles; ++mt) {
        bf16x8 fv = *(const bf16x8*)(facB + (size_t)(m0 + mt * 16 + lr16) * 32 + lq * 8);
        f32x4 acc[4];
#pragma unroll
        for (int q = 0; q < 4; ++q) acc[q] = (f32x4){0.f, 0.f, 0.f, 0.f};
#pragma unroll
        for (int q = 0; q < 4; ++q)  // D-row = n, D-col = m
          acc[q] = __builtin_amdgcn_mfma_f32_16x16x32_bf16(wv[q], fv, acc[q], 0, 0, 0);
        int m = m0 + mt * 16 + lr16;
#pragma unroll
        for (int q = 0; q < 4; ++q) {
          bf16x4 v;
#pragma unroll
          for (int e = 0; e < 4; ++e) v[e] = (__bf16)acc[q][e];
          *(bf16x4*)(At + (size_t)m * 4096 + n0w + q * 16 + 4 * lq) = v;
        }
      }
    } else {                       // means: ljm/lim bf16 [128][32]
      const float* lj = ws + WS_LJ;
      const float* li = ws + WS_LI;
      __bf16* dm = B16 + BF_LJM;
      __bf16* di = B16 + BF_LIM;
      for (int k = 0; k < 16; ++k) {
        int idx = k * 256 + t;
        dm[idx] = (__bf16)(0.25f * (lj[idx] + lj[4096 + idx] + lj[8192 + idx] + lj[12288 + idx]));
        di[idx] = (__bf16)(0.25f * (li[idx] + li[4096 + idx] + li[8192 + idx] + li[12288 + idx]));
      }
    }
  }
  grid_barrier(cnt + 1, GRID);

  // ===================== phase 3: the four outer-product quadrants ==========
  for (int u = b; u < 2048; u += GRID) {
    if (u < 1920) {                // rr / rl / lr  (K = 32)
      const __bf16* At;
      const __bf16* fc;
      const float* bias;
      float* outp;
      size_t jstr;
      if (u < 1152) {              // rr
        int i = u / 3, jt = u - 3 * i;
        At = B16 + BT_RR + (size_t)i * 4096;
        fc = B16 + BF_RJ + jt * 4096;
        bias = rrb; outp = out + ((size_t)i * NTOT + jt * 128) * OUTC; jstr = OUTC;
      } else if (u < 1536) {       // rl
        int i = u - 1152;
        At = B16 + BT_RL + (size_t)i * 4096;
        fc = B16 + BF_LJM;
        bias = rlb; outp = out + ((size_t)i * NTOT + NRES) * OUTC; jstr = OUTC;
      } else {                     // lr (transposed output)
        int i = u - 1536;
        At = B16 + BT_LR + (size_t)i * 4096;
        fc = B16 + BF_LIM;
        bias = lrb; outp = out + (size_t)NRES * NTOT * OUTC + (size_t)i * OUTC;
        jstr = (size_t)NTOT * OUTC;
      }
      bf16x8 fj[2];
#pragma unroll
      for (int jj = 0; jj < 2; ++jj)
        fj[jj] = *(const bf16x8*)(fc + (size_t)(w * 32 + jj * 16 + lr16) * 32 + lq * 8);
      f32x4 acc[2][8];
#pragma unroll
      for (int jj = 0; jj < 2; ++jj)
#pragma unroll
        for (int ot = 0; ot < 8; ++ot) acc[jj][ot] = (f32x4){0.f, 0.f, 0.f, 0.f};
#pragma unroll
      for (int oc = 0; oc < 2; ++oc) {
        bf16x8 av[4];
#pragma unroll
        for (int o4 = 0; o4 < 4; ++o4)
          av[o4] = *(const bf16x8*)(At + (size_t)((oc * 4 + o4) * 16 + lr16) * 32 + lq * 8);
#pragma unroll
        for (int jj = 0; jj < 2; ++jj)
#pragma unroll
          for (int o4 = 0; o4 < 4; ++o4)  // D-row = o, D-col = j
            acc[jj][oc * 4 + o4] =
                __builtin_amdgcn_mfma_f32_16x16x32_bf16(av[o4], fj[jj], acc[jj][oc * 4 + o4], 0, 0, 0);
      }
#pragma unroll
      for (int jj = 0; jj < 2; ++jj) {
        int j = w * 32 + jj * 16 + lr16;
#pragma unroll
        for (int ot = 0; ot < 8; ++ot) {
          f32x4 b4 = *(const f32x4*)&bias[ot * 16 + 4 * lq];
          f32x4 v = acc[jj][ot] + b4;
          *(f32x4*)&outp[(size_t)j * jstr + ot * 16 + 4 * lq] = v;
        }
      }
    } else {                       // ll: K = 128 (4 m-slices of 32)
      int il = u - 1920;
      f32x4 acc[2][8];
#pragma unroll
      for (int jj = 0; jj < 2; ++jj)
#pragma unroll
        for (int ot = 0; ot < 8; ++ot) acc[jj][ot] = (f32x4){0.f, 0.f, 0.f, 0.f};
      for (int m = 0; m < 4; ++m) {
        const __bf16* At = B16 + BT_LL + (size_t)(m * 128 + il) * 4096;
        const __bf16* fc = B16 + BF_LJ + m * 4096;
        bf16x8 fj[2];
#pragma unroll
        for (int jj = 0; jj < 2; ++jj)
          fj[jj] = *(const bf16x8*)(fc + (size_t)(w * 32 + jj * 16 + lr16) * 32 + lq * 8);
#pragma unroll
        for (int oc = 0; oc < 2; ++oc) {
          bf16x8 av[4];
#pragma unroll
          for (int o4 = 0; o4 < 4; ++o4)
            av[o4] = *(const bf16x8*)(At + (size_t)((oc * 4 + o4) * 16 + lr16) * 32 + lq * 8);
#pragma unroll
          for (int jj = 0; jj < 2; ++jj)
#pragma unroll
            for (int o4 = 0; o4 < 4; ++o4)
              acc[jj][oc * 4 + o4] =
                  __builtin_amdgcn_mfma_f32_16x16x32_bf16(av[o4], fj[jj], acc[jj][oc * 4 + o4], 0, 0, 0);
        }
      }
      float* outp = out + ((size_t)(NRES + il) * NTOT + NRES) * OUTC;
#pragma unroll
      for (int jj = 0; jj < 2; ++jj) {
        int j = w * 32 + jj * 16 + lr16;
#pragma unroll
        for (int ot = 0; ot < 8; ++ot) {
          f32x4 b4 = *(const f32x4*)&llb[ot * 16 + 4 * lq];
          f32x4 v = 0.25f * acc[jj][ot] + b4;
          *(f32x4*)&outp[(size_t)j * OUTC + ot * 16 + 4 * lq] = v;
        }
      }
    }
  }
}

extern "C" void kernel_launch(void* const* d_in, const int* in_sizes, int n_in,
                              void* d_out, int out_size, void* d_ws, size_t ws_size,
                              hipStream_t stream) {
  const float* rec  = (const float*)d_in[0];
  const float* lig  = (const float*)d_in[1];
  const float* rl1w = (const float*)d_in[3];
  const float* rl1b = (const float*)d_in[4];
  const float* rl2w = (const float*)d_in[5];
  const float* rl2b = (const float*)d_in[6];
  const float* ll1w = (const float*)d_in[7];
  const float* ll1b = (const float*)d_in[8];
  const float* ll2w = (const float*)d_in[9];
  const float* ll2b = (const float*)d_in[10];
  const float* rrw  = (const float*)d_in[11];
  const float* rrb  = (const float*)d_in[12];
  const float* rlw  = (const float*)d_in[13];
  const float* rlb  = (const float*)d_in[14];
  const float* lrw  = (const float*)d_in[15];
  const float* lrb  = (const float*)d_in[16];
  const float* llw  = (const float*)d_in[17];
  const float* llb  = (const float*)d_in[18];
  float* out = (float*)d_out;
  float* ws  = (float*)d_ws;

  // zero the barrier counters (graph-capture-safe memset node, every call)
  hipMemsetAsync((char*)d_ws + (size_t)WS_CNT * 4, 0, 64, stream);

  hipLaunchKernelGGL(fused_all, dim3(GRID), dim3(256), 0, stream,
                     rec, lig, rl1w, rl1b, rl2w, rl2b,
                     ll1w, ll1b, ll2w, ll2b,
                     rrw, rlw, lrw, llw,
                     rrb, rlb, lrb, llb, ws, out);
}

// Round 12
// 52.153 us; speedup vs baseline: 2.2266x; 2.2266x over previous
//
#include <hip/hip_runtime.h>

#define NRES 384
#define NLIG 128
#define INC 384
#define OUTC 128
#define NTOT 512

// ---- f32 ws regions (float offsets) ----
#define WS_RI   0           // [384][32]
#define WS_RJ   12288       // [384][32]
#define WS_LI   24576       // [512][32]  (m*128+nl)
#define WS_LJ   40960       // [512][32]
#define WS_BF16 57344       // bf16 area starts here (float offset)

// ---- bf16 regions (bf16-element offsets from WS_BF16) ----
#define BT_RR   0            // [384][o*32+y]
#define BT_RL   1572864
#define BT_LR   3145728
#define BT_LL   4718592      // [512][o*32+y]
#define BF_RJ   6815744      // [384][32]
#define BF_LJM  6828032      // [128][32]  mean_m l_j
#define BF_LIM  6832128      // [128][32]  mean_m l_i
#define BF_LJ   6836224      // [4*128][32]
#define BF_RI   6852608      // [384][32]
#define BF_LI   6864896      // [512][32]
#define BW_W    6881280      // 4 x [n=o*32+y][x] bf16
// end 7405568 bf16 -> total ws ~15.0 MB

typedef __bf16 bf16x8 __attribute__((ext_vector_type(8)));
typedef __bf16 bf16x4 __attribute__((ext_vector_type(4)));
typedef float  f32x4  __attribute__((ext_vector_type(4)));

__device__ inline bf16x8 cvt8(const float* p) {
  f32x4 a = *(const f32x4*)p, b = *(const f32x4*)(p + 4);
  bf16x8 r;
  r[0] = (__bf16)a[0]; r[1] = (__bf16)a[1]; r[2] = (__bf16)a[2]; r[3] = (__bf16)a[3];
  r[4] = (__bf16)b[0]; r[5] = (__bf16)b[1]; r[6] = (__bf16)b[2]; r[7] = (__bf16)b[3];
  return r;
}

// --- kP: projections (blocks 0..27) + W relayout, 1 o-row/block (28..539) --
__global__ __launch_bounds__(256) void kP_proj(
    const float* __restrict__ rec, const float* __restrict__ lig,
    const float* __restrict__ rl1w, const float* __restrict__ rl1b,
    const float* __restrict__ rl2w, const float* __restrict__ rl2b,
    const float* __restrict__ ll1w, const float* __restrict__ ll1b,
    const float* __restrict__ ll2w, const float* __restrict__ ll2b,
    const float* __restrict__ Wrr, const float* __restrict__ Wrl,
    const float* __restrict__ Wlr, const float* __restrict__ Wll,
    float* __restrict__ ws) {
  __shared__ float lds[32 * 33];
  int b = blockIdx.x, t = threadIdx.x;
  __bf16* B16 = (__bf16*)(ws + WS_BF16);
  if (b >= 28) {                   // W relayout: Wb[n=o*32+y][x] bf16
    int bb = b - 28;               // 0..511
    int tt = bb >> 7, o = bb & 127;
    const float* W = tt == 0 ? Wrr : tt == 1 ? Wrl : tt == 2 ? Wlr : Wll;
    __bf16* Wb = B16 + BW_W + tt * 131072;
#pragma unroll
    for (int k = 0; k < 4; ++k) {
      int idx = k * 256 + t;       // 0..1023 = x*32+y
      int x = idx >> 5, y = idx & 31;
      lds[y * 33 + x] = W[(size_t)o * 1024 + idx];
    }
    __syncthreads();
#pragma unroll
    for (int k = 0; k < 4; ++k) {
      int idx = k * 256 + t;       // 0..1023 = y*32+x
      int y = idx >> 5, x = idx & 31;
      Wb[(size_t)(o * 32 + y) * 32 + x] = (__bf16)lds[y * 33 + x];
    }
    return;
  }
  int l = t & 63, w = t >> 6;
  int lr16 = l & 15, lq = l >> 4;
  int pair = w >> 1, rh = w & 1;

  const float* in;
  const float *w1, *b1, *w2, *b2;
  float *o1, *o2;
  __bf16 *bf1, *bf2;
  int row0;
  if (b < 12) {
    row0 = b * 32;
    in = rec; w1 = rl1w; b1 = rl1b; w2 = rl2w; b2 = rl2b;
    o1 = ws + WS_RI; o2 = ws + WS_RJ;
    bf1 = B16 + BF_RI; bf2 = B16 + BF_RJ;
  } else {
    row0 = (b - 12) * 32;
    in = lig; w1 = ll1w; b1 = ll1b; w2 = ll2w; b2 = ll2b;
    o1 = ws + WS_LI; o2 = ws + WS_LJ;
    bf1 = B16 + BF_LI; bf2 = B16 + BF_LJ;
  }
  const float* wsrc = pair ? w2 : w1;
  const float* bsrc = pair ? b2 : b1;
  float* osrc = pair ? o2 : o1;
  __bf16* bdst = pair ? bf2 : bf1;
  int arow = row0 + rh * 16 + lr16;

  f32x4 acc[2];
#pragma unroll
  for (int ci = 0; ci < 2; ++ci) acc[ci] = (f32x4){0.f, 0.f, 0.f, 0.f};
  for (int ks = 0; ks < 12; ++ks) {
    bf16x8 af = cvt8(in + (size_t)arow * INC + ks * 32 + lq * 8);
#pragma unroll
    for (int ci = 0; ci < 2; ++ci) {
      int ch = ci * 16 + lr16;
      bf16x8 bf = cvt8(wsrc + (size_t)ch * INC + ks * 32 + lq * 8);
      acc[ci] = __builtin_amdgcn_mfma_f32_16x16x32_bf16(af, bf, acc[ci], 0, 0, 0);
    }
  }
#pragma unroll
  for (int ci = 0; ci < 2; ++ci) {
    int c = ci * 16 + lr16;
    float bias = bsrc[c];
#pragma unroll
    for (int e = 0; e < 4; ++e) {
      int r = row0 + rh * 16 + 4 * lq + e;
      float v = acc[ci][e] + bias;
      osrc[r * 32 + c] = v;
      bdst[r * 32 + c] = (__bf16)v;
    }
  }
}

// --- k2: At = facB @ Wb^T via MFMA, 256 blocks + means tail (b=256) --------
__global__ __launch_bounds__(256) void k2_makeA(float* __restrict__ ws) {
  int b = blockIdx.x, t = threadIdx.x;
  __bf16* B16 = (__bf16*)(ws + WS_BF16);
  if (b >= 256) {                  // means: ljm/lim bf16 [128][32]
    const float* lj = ws + WS_LJ;
    const float* li = ws + WS_LI;
    __bf16* dm = B16 + BF_LJM;
    __bf16* di = B16 + BF_LIM;
    for (int k = 0; k < 16; ++k) {
      int idx = k * 256 + t;
      dm[idx] = (__bf16)(0.25f * (lj[idx] + lj[4096 + idx] + lj[8192 + idx] + lj[12288 + idx]));
      di[idx] = (__bf16)(0.25f * (li[idx] + li[4096 + idx] + li[8192 + idx] + li[12288 + idx]));
    }
    return;
  }
  int tt = b >> 6, sub = b & 63;
  int nt = sub >> 2, mq = sub & 3;
  const __bf16* facB;
  __bf16* At;
  int M;
  if (tt == 0)      { facB = B16 + BF_RI; At = B16 + BT_RR; M = 384; }
  else if (tt == 1) { facB = B16 + BF_RI; At = B16 + BT_RL; M = 384; }
  else if (tt == 2) { facB = B16 + BF_RJ; At = B16 + BT_LR; M = 384; }
  else              { facB = B16 + BF_LI; At = B16 + BT_LL; M = 512; }
  const __bf16* Wb = B16 + BW_W + tt * 131072;
  int l = t & 63, w = t >> 6;
  int lr16 = l & 15, lq = l >> 4;
  int n0w = nt * 256 + w * 64;
  int mtiles = M >> 6;             // per quarter: M/4/16
  int m0 = mq * (M >> 2);

  bf16x8 wv[4];
#pragma unroll
  for (int q = 0; q < 4; ++q)
    wv[q] = *(const bf16x8*)(Wb + (size_t)(n0w + q * 16 + lr16) * 32 + lq * 8);

  for (int mt = 0; mt < mtiles; ++mt) {
    bf16x8 fv = *(const bf16x8*)(facB + (size_t)(m0 + mt * 16 + lr16) * 32 + lq * 8);
    f32x4 acc[4];
#pragma unroll
    for (int q = 0; q < 4; ++q) acc[q] = (f32x4){0.f, 0.f, 0.f, 0.f};
#pragma unroll
    for (int q = 0; q < 4; ++q)    // D-row = n, D-col = m
      acc[q] = __builtin_amdgcn_mfma_f32_16x16x32_bf16(wv[q], fv, acc[q], 0, 0, 0);
    int m = m0 + mt * 16 + lr16;
#pragma unroll
    for (int q = 0; q < 4; ++q) {
      bf16x4 v;
#pragma unroll
      for (int e = 0; e < 4; ++e) v[e] = (__bf16)acc[q][e];
      *(bf16x4*)(At + (size_t)m * 4096 + n0w + q * 16 + 4 * lq) = v;
    }
  }
}

// --- k3: four quadrants via MFMA; D-rows = o so stores are float4 ----------
__global__ __launch_bounds__(256) void k3_mfma(
    const float* __restrict__ ws, float* __restrict__ out,
    const float* __restrict__ rrb, const float* __restrict__ rlb,
    const float* __restrict__ lrb, const float* __restrict__ llb) {
  const __bf16* B16 = (const __bf16*)(ws + WS_BF16);
  int b = blockIdx.x, t = threadIdx.x;
  int l = t & 63, w = t >> 6;
  int lr16 = l & 15, lq = l >> 4;

  if (b < 1920) {                  // rr / rl / lr  (K = 32, one mfma per tile)
    const __bf16* At;
    const __bf16* fc;
    const float* bias;
    float* outp;
    size_t jstr;
    if (b < 1152) {                // rr
      int i = b / 3, jt = b - 3 * i;
      At = B16 + BT_RR + (size_t)i * 4096;
      fc = B16 + BF_RJ + jt * 4096;
      bias = rrb; outp = out + ((size_t)i * NTOT + jt * 128) * OUTC; jstr = OUTC;
    } else if (b < 1536) {         // rl
      int i = b - 1152;
      At = B16 + BT_RL + (size_t)i * 4096;
      fc = B16 + BF_LJM;
      bias = rlb; outp = out + ((size_t)i * NTOT + NRES) * OUTC; jstr = OUTC;
    } else {                       // lr (transposed output)
      int i = b - 1536;
      At = B16 + BT_LR + (size_t)i * 4096;
      fc = B16 + BF_LIM;
      bias = lrb; outp = out + (size_t)NRES * NTOT * OUTC + (size_t)i * OUTC;
      jstr = (size_t)NTOT * OUTC;
    }
    bf16x8 fj[2];
#pragma unroll
    for (int jj = 0; jj < 2; ++jj)
      fj[jj] = *(const bf16x8*)(fc + (size_t)(w * 32 + jj * 16 + lr16) * 32 + lq * 8);
    f32x4 acc[2][8];
#pragma unroll
    for (int jj = 0; jj < 2; ++jj)
#pragma unroll
      for (int ot = 0; ot < 8; ++ot) acc[jj][ot] = (f32x4){0.f, 0.f, 0.f, 0.f};
#pragma unroll
    for (int oc = 0; oc < 2; ++oc) {
      bf16x8 av[4];
#pragma unroll
      for (int o4 = 0; o4 < 4; ++o4)
        av[o4] = *(const bf16x8*)(At + (size_t)((oc * 4 + o4) * 16 + lr16) * 32 + lq * 8);
#pragma unroll
      for (int jj = 0; jj < 2; ++jj)
#pragma unroll
        for (int o4 = 0; o4 < 4; ++o4)   // D-row = o, D-col = j
          acc[jj][oc * 4 + o4] =
              __builtin_amdgcn_mfma_f32_16x16x32_bf16(av[o4], fj[jj], acc[jj][oc * 4 + o4], 0, 0, 0);
    }
#pragma unroll
    for (int jj = 0; jj < 2; ++jj) {
      int j = w * 32 + jj * 16 + lr16;
#pragma unroll
      for (int ot = 0; ot < 8; ++ot) {
        f32x4 b4 = *(const f32x4*)&bias[ot * 16 + 4 * lq];
        f32x4 v = acc[jj][ot] + b4;
        *(f32x4*)&outp[(size_t)j * jstr + ot * 16 + 4 * lq] = v;
      }
    }
  } else {                         // ll: K = 128 (4 m-slices of 32)
    int il = b - 1920;
    f32x4 acc[2][8];
#pragma unroll
    for (int jj = 0; jj < 2; ++jj)
#pragma unroll
      for (int ot = 0; ot < 8; ++ot) acc[jj][ot] = (f32x4){0.f, 0.f, 0.f, 0.f};
    for (int m = 0; m < 4; ++m) {
      const __bf16* At = B16 + BT_LL + (size_t)(m * 128 + il) * 4096;
      const __bf16* fc = B16 + BF_LJ + m * 4096;
      bf16x8 fj[2];
#pragma unroll
      for (int jj = 0; jj < 2; ++jj)
        fj[jj] = *(const bf16x8*)(fc + (size_t)(w * 32 + jj * 16 + lr16) * 32 + lq * 8);
#pragma unroll
      for (int oc = 0; oc < 2; ++oc) {
        bf16x8 av[4];
#pragma unroll
        for (int o4 = 0; o4 < 4; ++o4)
          av[o4] = *(const bf16x8*)(At + (size_t)((oc * 4 + o4) * 16 + lr16) * 32 + lq * 8);
#pragma unroll
        for (int jj = 0; jj < 2; ++jj)
#pragma unroll
          for (int o4 = 0; o4 < 4; ++o4)
            acc[jj][oc * 4 + o4] =
                __builtin_amdgcn_mfma_f32_16x16x32_bf16(av[o4], fj[jj], acc[jj][oc * 4 + o4], 0, 0, 0);
      }
    }
    float* outp = out + ((size_t)(NRES + il) * NTOT + NRES) * OUTC;
#pragma unroll
    for (int jj = 0; jj < 2; ++jj) {
      int j = w * 32 + jj * 16 + lr16;
#pragma unroll
      for (int ot = 0; ot < 8; ++ot) {
        f32x4 b4 = *(const f32x4*)&llb[ot * 16 + 4 * lq];
        f32x4 v = 0.25f * acc[jj][ot] + b4;
        *(f32x4*)&outp[(size_t)j * OUTC + ot * 16 + 4 * lq] = v;
      }
    }
  }
}

extern "C" void kernel_launch(void* const* d_in, const int* in_sizes, int n_in,
                              void* d_out, int out_size, void* d_ws, size_t ws_size,
                              hipStream_t stream) {
  const float* rec  = (const float*)d_in[0];
  const float* lig  = (const float*)d_in[1];
  const float* rl1w = (const float*)d_in[3];
  const float* rl1b = (const float*)d_in[4];
  const float* rl2w = (const float*)d_in[5];
  const float* rl2b = (const float*)d_in[6];
  const float* ll1w = (const float*)d_in[7];
  const float* ll1b = (const float*)d_in[8];
  const float* ll2w = (const float*)d_in[9];
  const float* ll2b = (const float*)d_in[10];
  const float* rrw  = (const float*)d_in[11];
  const float* rrb  = (const float*)d_in[12];
  const float* rlw  = (const float*)d_in[13];
  const float* rlb  = (const float*)d_in[14];
  const float* lrw  = (const float*)d_in[15];
  const float* lrb  = (const float*)d_in[16];
  const float* llw  = (const float*)d_in[17];
  const float* llb  = (const float*)d_in[18];
  float* out = (float*)d_out;
  float* ws  = (float*)d_ws;

  hipLaunchKernelGGL(kP_proj, dim3(540), dim3(256), 0, stream,
                     rec, lig, rl1w, rl1b, rl2w, rl2b, ll1w, ll1b, ll2w, ll2b,
                     rrw, rlw, lrw, llw, ws);
  hipLaunchKernelGGL(k2_makeA, dim3(257), dim3(256), 0, stream, ws);
  hipLaunchKernelGGL(k3_mfma, dim3(2048), dim3(256), 0, stream,
                     ws, out, rrb, rlb, lrb, llb);
}

// Round 13
// 50.897 us; speedup vs baseline: 2.2816x; 1.0247x over previous
//
#include <hip/hip_runtime.h>

#define NRES 384
#define NLIG 128
#define INC 384
#define OUTC 128
#define NTOT 512

// ---- f32 ws regions (float offsets) ----
#define WS_RI   0           // [384][32]
#define WS_RJ   12288       // [384][32]
#define WS_LI   24576       // [512][32]  (m*128+nl)
#define WS_LJ   40960       // [512][32]
#define WS_BF16 57344       // bf16 area starts here (float offset)

// ---- bf16 regions (bf16-element offsets from WS_BF16) ----
#define BT_RR   0            // [384][o*32+y]
#define BT_RL   1572864
#define BT_LR   3145728
#define BT_LL   4718592      // [512][o*32+y]
#define BF_RJ   6815744      // [384][32]
#define BF_LJM  6828032      // [128][32]  mean_m l_j
#define BF_LIM  6832128      // [128][32]  mean_m l_i
#define BF_LJ   6836224      // [4*128][32]
#define BF_RI   6852608      // [384][32]
#define BF_LI   6864896      // [512][32]
#define BW_W    6881280      // 4 x [n=o*32+y][x] bf16
// end 7405568 bf16 -> total ws ~15.0 MB

typedef __bf16 bf16x8 __attribute__((ext_vector_type(8)));
typedef __bf16 bf16x4 __attribute__((ext_vector_type(4)));
typedef float  f32x4  __attribute__((ext_vector_type(4)));

__device__ inline bf16x8 cvt8(const float* p) {
  f32x4 a = *(const f32x4*)p, b = *(const f32x4*)(p + 4);
  bf16x8 r;
  r[0] = (__bf16)a[0]; r[1] = (__bf16)a[1]; r[2] = (__bf16)a[2]; r[3] = (__bf16)a[3];
  r[4] = (__bf16)b[0]; r[5] = (__bf16)b[1]; r[6] = (__bf16)b[2]; r[7] = (__bf16)b[3];
  return r;
}

// --- kP: projections (blocks 0..27) + W relayout, 1 o-row/block (28..539) --
__global__ __launch_bounds__(256) void kP_proj(
    const float* __restrict__ rec, const float* __restrict__ lig,
    const float* __restrict__ rl1w, const float* __restrict__ rl1b,
    const float* __restrict__ rl2w, const float* __restrict__ rl2b,
    const float* __restrict__ ll1w, const float* __restrict__ ll1b,
    const float* __restrict__ ll2w, const float* __restrict__ ll2b,
    const float* __restrict__ Wrr, const float* __restrict__ Wrl,
    const float* __restrict__ Wlr, const float* __restrict__ Wll,
    float* __restrict__ ws) {
  __shared__ float lds[32 * 33];
  int b = blockIdx.x, t = threadIdx.x;
  __bf16* B16 = (__bf16*)(ws + WS_BF16);
  if (b >= 28) {                   // W relayout: Wb[n=o*32+y][x] bf16
    int bb = b - 28;               // 0..511
    int tt = bb >> 7, o = bb & 127;
    const float* W = tt == 0 ? Wrr : tt == 1 ? Wrl : tt == 2 ? Wlr : Wll;
    __bf16* Wb = B16 + BW_W + tt * 131072;
#pragma unroll
    for (int k = 0; k < 4; ++k) {
      int idx = k * 256 + t;       // 0..1023 = x*32+y
      int x = idx >> 5, y = idx & 31;
      lds[y * 33 + x] = W[(size_t)o * 1024 + idx];
    }
    __syncthreads();
#pragma unroll
    for (int k = 0; k < 4; ++k) {
      int idx = k * 256 + t;       // 0..1023 = y*32+x
      int y = idx >> 5, x = idx & 31;
      Wb[(size_t)(o * 32 + y) * 32 + x] = (__bf16)lds[y * 33 + x];
    }
    return;
  }
  int l = t & 63, w = t >> 6;
  int lr16 = l & 15, lq = l >> 4;
  int pair = w >> 1, rh = w & 1;

  const float* in;
  const float *w1, *b1, *w2, *b2;
  float *o1, *o2;
  __bf16 *bf1, *bf2;
  int row0;
  if (b < 12) {
    row0 = b * 32;
    in = rec; w1 = rl1w; b1 = rl1b; w2 = rl2w; b2 = rl2b;
    o1 = ws + WS_RI; o2 = ws + WS_RJ;
    bf1 = B16 + BF_RI; bf2 = B16 + BF_RJ;
  } else {
    row0 = (b - 12) * 32;
    in = lig; w1 = ll1w; b1 = ll1b; w2 = ll2w; b2 = ll2b;
    o1 = ws + WS_LI; o2 = ws + WS_LJ;
    bf1 = B16 + BF_LI; bf2 = B16 + BF_LJ;
  }
  const float* wsrc = pair ? w2 : w1;
  const float* bsrc = pair ? b2 : b1;
  float* osrc = pair ? o2 : o1;
  __bf16* bdst = pair ? bf2 : bf1;
  int arow = row0 + rh * 16 + lr16;

  f32x4 acc[2];
#pragma unroll
  for (int ci = 0; ci < 2; ++ci) acc[ci] = (f32x4){0.f, 0.f, 0.f, 0.f};
  for (int ks = 0; ks < 12; ++ks) {
    bf16x8 af = cvt8(in + (size_t)arow * INC + ks * 32 + lq * 8);
#pragma unroll
    for (int ci = 0; ci < 2; ++ci) {
      int ch = ci * 16 + lr16;
      bf16x8 bf = cvt8(wsrc + (size_t)ch * INC + ks * 32 + lq * 8);
      acc[ci] = __builtin_amdgcn_mfma_f32_16x16x32_bf16(af, bf, acc[ci], 0, 0, 0);
    }
  }
#pragma unroll
  for (int ci = 0; ci < 2; ++ci) {
    int c = ci * 16 + lr16;
    float bias = bsrc[c];
#pragma unroll
    for (int e = 0; e < 4; ++e) {
      int r = row0 + rh * 16 + 4 * lq + e;
      float v = acc[ci][e] + bias;
      osrc[r * 32 + c] = v;
      bdst[r * 32 + c] = (__bf16)v;
    }
  }
}

// --- k2: At = facB @ Wb^T via MFMA; LDS-staged tile -> dense 512B-run stores
#define TSTR 264   // bf16 row stride: 528B, 16B-aligned rows
__global__ __launch_bounds__(256) void k2_makeA(float* __restrict__ ws) {
  __shared__ __bf16 tile[128 * TSTR];    // 66 KB
  int b = blockIdx.x, t = threadIdx.x;
  __bf16* B16 = (__bf16*)(ws + WS_BF16);
  if (b >= 256) {                  // means: ljm/lim bf16 [128][32]
    const float* lj = ws + WS_LJ;
    const float* li = ws + WS_LI;
    __bf16* dm = B16 + BF_LJM;
    __bf16* di = B16 + BF_LIM;
    for (int k = 0; k < 16; ++k) {
      int idx = k * 256 + t;
      dm[idx] = (__bf16)(0.25f * (lj[idx] + lj[4096 + idx] + lj[8192 + idx] + lj[12288 + idx]));
      di[idx] = (__bf16)(0.25f * (li[idx] + li[4096 + idx] + li[8192 + idx] + li[12288 + idx]));
    }
    return;
  }
  int tt = b >> 6, sub = b & 63;
  int nt = sub >> 2, mq = sub & 3;
  const __bf16* facB;
  __bf16* At;
  int M;
  if (tt == 0)      { facB = B16 + BF_RI; At = B16 + BT_RR; M = 384; }
  else if (tt == 1) { facB = B16 + BF_RI; At = B16 + BT_RL; M = 384; }
  else if (tt == 2) { facB = B16 + BF_RJ; At = B16 + BT_LR; M = 384; }
  else              { facB = B16 + BF_LI; At = B16 + BT_LL; M = 512; }
  const __bf16* Wb = B16 + BW_W + tt * 131072;
  int l = t & 63, w = t >> 6;
  int lr16 = l & 15, lq = l >> 4;
  int nw = w * 64;                 // local n base for this wave
  int n0w = nt * 256 + nw;         // global n base
  int mspan = M >> 2;              // 96 or 128
  int mtiles = M >> 6;             // mspan/16
  int m0 = mq * mspan;

  bf16x8 wv[4];
#pragma unroll
  for (int q = 0; q < 4; ++q)
    wv[q] = *(const bf16x8*)(Wb + (size_t)(n0w + q * 16 + lr16) * 32 + lq * 8);

  for (int mt = 0; mt < mtiles; ++mt) {
    bf16x8 fv = *(const bf16x8*)(facB + (size_t)(m0 + mt * 16 + lr16) * 32 + lq * 8);
    f32x4 acc[4];
#pragma unroll
    for (int q = 0; q < 4; ++q) acc[q] = (f32x4){0.f, 0.f, 0.f, 0.f};
#pragma unroll
    for (int q = 0; q < 4; ++q)    // D-row = n, D-col = m
      acc[q] = __builtin_amdgcn_mfma_f32_16x16x32_bf16(wv[q], fv, acc[q], 0, 0, 0);
    int ml = mt * 16 + lr16;       // local m row
#pragma unroll
    for (int q = 0; q < 4; ++q) {
      bf16x4 v;
#pragma unroll
      for (int e = 0; e < 4; ++e) v[e] = (__bf16)acc[q][e];
      *(bf16x4*)&tile[ml * TSTR + nw + q * 16 + 4 * lq] = v;
    }
  }
  __syncthreads();
  // dense copy-out: 512B-contiguous run per row, rows 8KB apart
  int total8 = mspan * 32;         // 8-bf16 units (row = 32 units of 16B)
  for (int idx = t; idx < total8; idx += 256) {
    int m = idx >> 5, nl = (idx & 31) * 8;
    bf16x8 v = *(const bf16x8*)&tile[m * TSTR + nl];
    *(bf16x8*)(At + (size_t)(m0 + m) * 4096 + nt * 256 + nl) = v;
  }
}

// --- k3: four quadrants via MFMA; D-rows = o so stores are float4 ----------
__global__ __launch_bounds__(256) void k3_mfma(
    const float* __restrict__ ws, float* __restrict__ out,
    const float* __restrict__ rrb, const float* __restrict__ rlb,
    const float* __restrict__ lrb, const float* __restrict__ llb) {
  const __bf16* B16 = (const __bf16*)(ws + WS_BF16);
  int b = blockIdx.x, t = threadIdx.x;
  int l = t & 63, w = t >> 6;
  int lr16 = l & 15, lq = l >> 4;

  if (b < 1920) {                  // rr / rl / lr  (K = 32, one mfma per tile)
    const __bf16* At;
    const __bf16* fc;
    const float* bias;
    float* outp;
    size_t jstr;
    if (b < 1152) {                // rr
      int i = b / 3, jt = b - 3 * i;
      At = B16 + BT_RR + (size_t)i * 4096;
      fc = B16 + BF_RJ + jt * 4096;
      bias = rrb; outp = out + ((size_t)i * NTOT + jt * 128) * OUTC; jstr = OUTC;
    } else if (b < 1536) {         // rl
      int i = b - 1152;
      At = B16 + BT_RL + (size_t)i * 4096;
      fc = B16 + BF_LJM;
      bias = rlb; outp = out + ((size_t)i * NTOT + NRES) * OUTC; jstr = OUTC;
    } else {                       // lr (transposed output)
      int i = b - 1536;
      At = B16 + BT_LR + (size_t)i * 4096;
      fc = B16 + BF_LIM;
      bias = lrb; outp = out + (size_t)NRES * NTOT * OUTC + (size_t)i * OUTC;
      jstr = (size_t)NTOT * OUTC;
    }
    bf16x8 fj[2];
#pragma unroll
    for (int jj = 0; jj < 2; ++jj)
      fj[jj] = *(const bf16x8*)(fc + (size_t)(w * 32 + jj * 16 + lr16) * 32 + lq * 8);
    f32x4 acc[2][8];
#pragma unroll
    for (int jj = 0; jj < 2; ++jj)
#pragma unroll
      for (int ot = 0; ot < 8; ++ot) acc[jj][ot] = (f32x4){0.f, 0.f, 0.f, 0.f};
#pragma unroll
    for (int oc = 0; oc < 2; ++oc) {
      bf16x8 av[4];
#pragma unroll
      for (int o4 = 0; o4 < 4; ++o4)
        av[o4] = *(const bf16x8*)(At + (size_t)((oc * 4 + o4) * 16 + lr16) * 32 + lq * 8);
#pragma unroll
      for (int jj = 0; jj < 2; ++jj)
#pragma unroll
        for (int o4 = 0; o4 < 4; ++o4)   // D-row = o, D-col = j
          acc[jj][oc * 4 + o4] =
              __builtin_amdgcn_mfma_f32_16x16x32_bf16(av[o4], fj[jj], acc[jj][oc * 4 + o4], 0, 0, 0);
    }
#pragma unroll
    for (int jj = 0; jj < 2; ++jj) {
      int j = w * 32 + jj * 16 + lr16;
#pragma unroll
      for (int ot = 0; ot < 8; ++ot) {
        f32x4 b4 = *(const f32x4*)&bias[ot * 16 + 4 * lq];
        f32x4 v = acc[jj][ot] + b4;
        *(f32x4*)&outp[(size_t)j * jstr + ot * 16 + 4 * lq] = v;
      }
    }
  } else {                         // ll: K = 128 (4 m-slices of 32)
    int il = b - 1920;
    f32x4 acc[2][8];
#pragma unroll
    for (int jj = 0; jj < 2; ++jj)
#pragma unroll
      for (int ot = 0; ot < 8; ++ot) acc[jj][ot] = (f32x4){0.f, 0.f, 0.f, 0.f};
    for (int m = 0; m < 4; ++m) {
      const __bf16* At = B16 + BT_LL + (size_t)(m * 128 + il) * 4096;
      const __bf16* fc = B16 + BF_LJ + m * 4096;
      bf16x8 fj[2];
#pragma unroll
      for (int jj = 0; jj < 2; ++jj)
        fj[jj] = *(const bf16x8*)(fc + (size_t)(w * 32 + jj * 16 + lr16) * 32 + lq * 8);
#pragma unroll
      for (int oc = 0; oc < 2; ++oc) {
        bf16x8 av[4];
#pragma unroll
        for (int o4 = 0; o4 < 4; ++o4)
          av[o4] = *(const bf16x8*)(At + (size_t)((oc * 4 + o4) * 16 + lr16) * 32 + lq * 8);
#pragma unroll
        for (int jj = 0; jj < 2; ++jj)
#pragma unroll
          for (int o4 = 0; o4 < 4; ++o4)
            acc[jj][oc * 4 + o4] =
                __builtin_amdgcn_mfma_f32_16x16x32_bf16(av[o4], fj[jj], acc[jj][oc * 4 + o4], 0, 0, 0);
      }
    }
    float* outp = out + ((size_t)(NRES + il) * NTOT + NRES) * OUTC;
#pragma unroll
    for (int jj = 0; jj < 2; ++jj) {
      int j = w * 32 + jj * 16 + lr16;
#pragma unroll
      for (int ot = 0; ot < 8; ++ot) {
        f32x4 b4 = *(const f32x4*)&llb[ot * 16 + 4 * lq];
        f32x4 v = 0.25f * acc[jj][ot] + b4;
        *(f32x4*)&outp[(size_t)j * OUTC + ot * 16 + 4 * lq] = v;
      }
    }
  }
}

extern "C" void kernel_launch(void* const* d_in, const int* in_sizes, int n_in,
                              void* d_out, int out_size, void* d_ws, size_t ws_size,
                              hipStream_t stream) {
  const float* rec  = (const float*)d_in[0];
  const float* lig  = (const float*)d_in[1];
  const float* rl1w = (const float*)d_in[3];
  const float* rl1b = (const float*)d_in[4];
  const float* rl2w = (const float*)d_in[5];
  const float* rl2b = (const float*)d_in[6];
  const float* ll1w = (const float*)d_in[7];
  const float* ll1b = (const float*)d_in[8];
  const float* ll2w = (const float*)d_in[9];
  const float* ll2b = (const float*)d_in[10];
  const float* rrw  = (const float*)d_in[11];
  const float* rrb  = (const float*)d_in[12];
  const float* rlw  = (const float*)d_in[13];
  const float* rlb  = (const float*)d_in[14];
  const float* lrw  = (const float*)d_in[15];
  const float* lrb  = (const float*)d_in[16];
  const float* llw  = (const float*)d_in[17];
  const float* llb  = (const float*)d_in[18];
  float* out = (float*)d_out;
  float* ws  = (float*)d_ws;

  hipLaunchKernelGGL(kP_proj, dim3(540), dim3(256), 0, stream,
                     rec, lig, rl1w, rl1b, rl2w, rl2b, ll1w, ll1b, ll2w, ll2b,
                     rrw, rlw, lrw, llw, ws);
  hipLaunchKernelGGL(k2_makeA, dim3(257), dim3(256), 0, stream, ws);
  hipLaunchKernelGGL(k3_mfma, dim3(2048), dim3(256), 0, stream,
                     ws, out, rrb, rlb, lrb, llb);
}